// Round 19
// baseline (1330.051 us; speedup 1.0000x reference)
//
#include <hip/hip_runtime.h>
#include <stdint.h>

typedef unsigned short u16;
typedef float f32x4 __attribute__((ext_vector_type(4)));
typedef short bf16x8 __attribute__((ext_vector_type(8)));

#define MEMFENCE asm volatile("" ::: "memory")

// ---------- helpers ----------
__device__ __forceinline__ u16 f2bu(float f) {           // fp32 -> bf16 (RNE)
  uint32_t x = __builtin_bit_cast(uint32_t, f);
  x += 0x7fffu + ((x >> 16) & 1u);
  return (u16)(x >> 16);
}
__device__ __forceinline__ float b2f(u16 u) {            // bf16 -> fp32 (exact)
  return __builtin_bit_cast(float, (uint32_t)u << 16);
}
__device__ __forceinline__ void gll16(const void* g, void* l) {
  __builtin_amdgcn_global_load_lds(
      (const __attribute__((address_space(1))) void*)g,
      (__attribute__((address_space(3))) void*)l, 16, 0, 0);
}

// ---------- fused fp32 -> bf16 convert (3 tensors, one launch) ----------
__global__ __launch_bounds__(256) void cvt_all_kernel(
    const float* __restrict__ s, u16* __restrict__ os, int ns4,
    const float* __restrict__ w1, u16* __restrict__ o1, int n14,
    const float* __restrict__ w2, u16* __restrict__ o2, int n24) {
  const int stride = gridDim.x * 256;
  const int t0 = blockIdx.x * 256 + threadIdx.x;
  for (int i = t0; i < ns4; i += stride) {
    f32x4 f = __builtin_nontemporal_load(&reinterpret_cast<const f32x4*>(s)[i]);
    ushort4 o;
    o.x = f2bu(f.x); o.y = f2bu(f.y); o.z = f2bu(f.z); o.w = f2bu(f.w);
    reinterpret_cast<ushort4*>(os)[i] = o;
  }
  for (int i = t0; i < n14; i += stride) {
    f32x4 f = __builtin_nontemporal_load(&reinterpret_cast<const f32x4*>(w1)[i]);
    ushort4 o;
    o.x = f2bu(f.x); o.y = f2bu(f.y); o.z = f2bu(f.z); o.w = f2bu(f.w);
    reinterpret_cast<ushort4*>(o1)[i] = o;
  }
  for (int i = t0; i < n24; i += stride) {
    f32x4 f = __builtin_nontemporal_load(&reinterpret_cast<const f32x4*>(w2)[i]);
    ushort4 o;
    o.x = f2bu(f.x); o.y = f2bu(f.y); o.z = f2bu(f.z); o.w = f2bu(f.w);
    reinterpret_cast<ushort4*>(o2)[i] = o;
  }
}

// ---------- 256x256 GEMM, 16 waves, 64x64 wave-tile, BK=32, 3-buffer ------
// C[m,n] = sum_k A[m,k]*B[n,k] + bias[n], bf16 in/out, fp32 accum.
// T4 isolation vs r10 (same geometry/swizzle, vmcnt(0)-drain, 731us):
// depth-2 prefetch + counted vmcnt(2) -- loads get ~2 iterations of slack
// instead of <1, so the per-iter barrier no longer eats HBM latency tails.
// Wait ledger (2 gll/STAGE/thread, FIFO): prologue stages t0,t1, vmcnt(2)
// certifies t0. Iter t: STAGE(t+2) -> 4 outstanding; compute t; vmcnt(2)
// certifies t+1 (t+2 stays in flight); t==NT-2: no stage -> vmcnt(0)
// certifies NT-1. WAR: STAGE(t+2) overwrites buf of t-1 whose ds_reads
// completed before the previous barrier (MFMA data-dep). Swizzle (r10-
// proven): source c4' = c4 ^ ((row>>1)&3), read slot2 = kg ^ ((fr>>1)&3).
__global__ __launch_bounds__(1024, 4) void gemm256_bt_bias(
    const u16* __restrict__ A, const u16* __restrict__ Bw,
    const float* __restrict__ bias, u16* __restrict__ C,
    int N, int K, int lda, int ldc, int ntn) {
  __shared__ u16 lds[3][2][8192];   // [buf][A=0/B=1][256 rows * 32 cols] = 96KB
  const int tid = threadIdx.x;
  const int lane = tid & 63, wid = tid >> 6;   // wid 0..15
  const int wr = wid >> 2, wc = wid & 3;        // wave grid 4 (M) x 4 (N)
  const int fr = lane & 15, kg = lane >> 4;

  // XCD-aware swizzle (grid % 8 == 0 for both calls)
  const int cpx = (int)gridDim.x >> 3;
  const int bid = blockIdx.x;
  const int sid = (bid & 7) * cpx + (bid >> 3);
  const int mt = sid / ntn, nt = sid % ntn;

  // staging: slot s = tid; row = s>>2 (0..255), c4 = s&3.
  // source c4 pre-swizzled: c4' = c4 ^ ((row>>1)&3)
  const int srow = tid >> 2;
  const int scol = (tid & 3) ^ ((tid >> 3) & 3);
  const u16* Ag = A + (size_t)(mt * 256 + srow) * lda + scol * 8;
  const u16* Bg = Bw + (size_t)(nt * 256 + srow) * K + scol * 8;

  // fragment read offsets (u16), same involution on the read side
  const int sw = (fr >> 1) & 3;
  const int kgs = (kg ^ sw) * 8;
  const int aoff = (wr * 64 + fr) * 32 + kgs;
  const int boff = (wc * 64 + fr) * 32 + kgs;

  f32x4 acc[4][4];
#pragma unroll
  for (int i = 0; i < 4; i++)
#pragma unroll
    for (int j = 0; j < 4; j++) acc[i][j] = f32x4{0.f, 0.f, 0.f, 0.f};

  const int NT = K >> 5;

#define STAGE(b, kt) do {                                   \
    gll16(Ag + (size_t)(kt) * 32, &lds[(b)][0][wid * 512]); \
    gll16(Bg + (size_t)(kt) * 32, &lds[(b)][1][wid * 512]); \
  } while (0)

  // prologue: tiles 0 and 1; certify tile 0 (vmcnt(2) leaves tile 1 in flight)
  STAGE(0, 0);
  STAGE(1, 1);
  asm volatile("s_waitcnt vmcnt(2)" ::: "memory");
  __builtin_amdgcn_s_barrier();
  MEMFENCE;

  int cur = 0, stg = 2;   // stg = (cur+2)%3
  for (int t = 0; t < NT; t++) {
    if (t + 2 < NT) STAGE(stg, t + 2);
    const u16* As = &lds[cur][0][0];
    const u16* Bs = &lds[cur][1][0];
    bf16x8 a[4], b[4];
#pragma unroll
    for (int nj = 0; nj < 4; nj++)
      b[nj] = *(const bf16x8*)&Bs[boff + nj * 512];
#pragma unroll
    for (int mi = 0; mi < 4; mi++)
      a[mi] = *(const bf16x8*)&As[aoff + mi * 512];
    __builtin_amdgcn_s_setprio(1);
#pragma unroll
    for (int mi = 0; mi < 4; mi++)
#pragma unroll
      for (int nj = 0; nj < 4; nj++)
        acc[mi][nj] = __builtin_amdgcn_mfma_f32_16x16x32_bf16(
            a[mi], b[nj], acc[mi][nj], 0, 0, 0);
    __builtin_amdgcn_s_setprio(0);
    if (t < NT - 2)      asm volatile("s_waitcnt vmcnt(2)" ::: "memory");
    else                 asm volatile("s_waitcnt vmcnt(0)" ::: "memory");
    __builtin_amdgcn_s_barrier();
    MEMFENCE;
    cur = (cur == 2) ? 0 : cur + 1;
    stg = (stg == 2) ? 0 : stg + 1;
  }
#undef STAGE

  // C/D layout per 16x16 frag: col = lane&15, row = (lane>>4)*4 + reg
  const int crow0 = mt * 256 + wr * 64 + kg * 4;
  const int ccol0 = nt * 256 + wc * 64 + fr;
#pragma unroll
  for (int nj = 0; nj < 4; nj++) {
    const int col = ccol0 + nj * 16;
    const float bb = bias[col];
#pragma unroll
    for (int mi = 0; mi < 4; mi++) {
      const int r0 = crow0 + mi * 16;
      f32x4 v = acc[mi][nj];
#pragma unroll
      for (int r = 0; r < 4; r++)
        C[(size_t)(r0 + r) * ldc + col] = f2bu(v[r] + bb);
    }
  }
}

// ---------- tiny attention: S=3, 16 heads of d=64, 16B/lane ----------
__global__ __launch_bounds__(256) void attn3_kernel(
    u16* __restrict__ qkv) {
  const int tid = threadIdx.x;
  const int lane = tid & 63, wid = tid >> 6;
  const int nunit = 32768 * 2;
  for (int unit = blockIdx.x * 4 + wid; unit < nunit; unit += gridDim.x * 4) {
    const int b = unit >> 1, hf = unit & 1;
    const int colb = hf * 512 + (lane >> 3) * 64 + (lane & 7) * 8;
    const size_t base = (size_t)b * 9216 + colb;

    float q[3][8], k[3][8], v[3][8];
#pragma unroll
    for (int s = 0; s < 3; s++) {
      bf16x8 uq = __builtin_nontemporal_load(
          (const bf16x8*)(qkv + base + (size_t)s * 3072));
      bf16x8 uk = __builtin_nontemporal_load(
          (const bf16x8*)(qkv + base + (size_t)s * 3072 + 1024));
      bf16x8 uv = __builtin_nontemporal_load(
          (const bf16x8*)(qkv + base + (size_t)s * 3072 + 2048));
#pragma unroll
      for (int e = 0; e < 8; e++) {
        q[s][e] = b2f((u16)uq[e]);
        k[s][e] = b2f((u16)uk[e]);
        v[s][e] = b2f((u16)uv[e]);
      }
    }

    float sc[3][3];
#pragma unroll
    for (int i = 0; i < 3; i++)
#pragma unroll
      for (int j = 0; j < 3; j++) {
        float p = 0.f;
#pragma unroll
        for (int e = 0; e < 8; e++) p += q[i][e] * k[j][e];
        p += __shfl_xor(p, 1);
        p += __shfl_xor(p, 2);
        p += __shfl_xor(p, 4);   // 8-lane group = one head's 64 dims
        sc[i][j] = p;
      }

    float o[3][8];
#pragma unroll
    for (int i = 0; i < 3; i++) {
      float mx = fmaxf(sc[i][0], fmaxf(sc[i][1], sc[i][2]));
      float e0 = __expf((sc[i][0] - mx) * 0.125f);
      float e1 = __expf((sc[i][1] - mx) * 0.125f);
      float e2 = __expf((sc[i][2] - mx) * 0.125f);
      float inv = 1.f / (e0 + e1 + e2);
      e0 *= inv; e1 *= inv; e2 *= inv;
#pragma unroll
      for (int e = 0; e < 8; e++)
        o[i][e] = e0 * v[0][e] + e1 * v[1][e] + e2 * v[2][e];
    }

#pragma unroll
    for (int i = 0; i < 3; i++) {
      bf16x8 ov;
#pragma unroll
      for (int e = 0; e < 8; e++) ov[e] = (short)f2bu(o[i][e]);
      *(bf16x8*)(qkv + base + (size_t)i * 3072 + 1024) = ov;
    }
  }
}

// ---------- residual + LayerNorm: wave per row of 1024, 16B loads ----------
__global__ __launch_bounds__(256) void ln_kernel(
    const u16* __restrict__ slots_bf, const u16* __restrict__ ao,
    const float* __restrict__ g, const float* __restrict__ bvec,
    float* __restrict__ out) {
  const int tid = threadIdx.x;
  const int lane = tid & 63, wid = tid >> 6;
  const int row = blockIdx.x * 4 + wid;
  const size_t rb = (size_t)row * 1024;
  const size_t ab = (size_t)row * 3072;

  float y[16];
  float sum = 0.f, sq = 0.f;
#pragma unroll
  for (int c = 0; c < 2; c++) {
    const int col = c * 512 + lane * 8;
    bf16x8 s8 = __builtin_nontemporal_load((const bf16x8*)(slots_bf + rb + col));
    bf16x8 a8 = __builtin_nontemporal_load((const bf16x8*)(ao + ab + col));
#pragma unroll
    for (int e = 0; e < 8; e++) {
      float yv = b2f((u16)s8[e]) + b2f((u16)a8[e]);
      y[c * 8 + e] = yv;
      sum += yv;
      sq += yv * yv;
    }
  }
#pragma unroll
  for (int m = 1; m < 64; m <<= 1) {
    sum += __shfl_xor(sum, m);
    sq  += __shfl_xor(sq, m);
  }
  const float mu = sum * (1.0f / 1024.0f);
  const float var = sq * (1.0f / 1024.0f) - mu * mu;
  const float rs = rsqrtf(var + 1e-5f);
#pragma unroll
  for (int c = 0; c < 2; c++) {
    const int col = c * 512 + lane * 8;
#pragma unroll
    for (int h = 0; h < 2; h++) {
      const float* gp = g + col + h * 4;
      const float* bp = bvec + col + h * 4;
      f32x4 gg = *reinterpret_cast<const f32x4*>(gp);
      f32x4 bb = *reinterpret_cast<const f32x4*>(bp);
      f32x4 ov;
      ov.x = (y[c * 8 + h * 4 + 0] - mu) * rs * gg.x + bb.x;
      ov.y = (y[c * 8 + h * 4 + 1] - mu) * rs * gg.y + bb.y;
      ov.z = (y[c * 8 + h * 4 + 2] - mu) * rs * gg.z + bb.z;
      ov.w = (y[c * 8 + h * 4 + 3] - mu) * rs * gg.w + bb.w;
      __builtin_nontemporal_store(ov, reinterpret_cast<f32x4*>(out + rb + col + h * 4));
    }
  }
}

extern "C" void kernel_launch(void* const* d_in, const int* in_sizes, int n_in,
                              void* d_out, int out_size, void* d_ws, size_t ws_size,
                              hipStream_t stream) {
  const float* slots = (const float*)d_in[0];
  const float* in_w  = (const float*)d_in[1];
  const float* in_b  = (const float*)d_in[2];
  const float* out_w = (const float*)d_in[3];
  const float* out_b = (const float*)d_in[4];
  const float* ln_g  = (const float*)d_in[5];
  const float* ln_b  = (const float*)d_in[6];
  float* out = (float*)d_out;

  const int M = 32768 * 3;  // 98304 rows

  // workspace layout:
  //   Abf   [M*1024 bf16] = 201,326,592 B   (stays live: bf16 slots for ln)
  //   Winb  [3072*1024]   =   6,291,456 B
  //   Woutb [1024*1024]   =   2,097,152 B
  //   qkv   [M*3072]      = 603,979,776 B   (k-slice reused as ctx,
  //                                          q-slice reused as attn_out)
  char* ws = (char*)d_ws;
  u16* Abf   = (u16*)ws;
  u16* Winb  = (u16*)(ws + 201326592);
  u16* Woutb = (u16*)(ws + 207618048);
  u16* qkv   = (u16*)(ws + 209715200);

  cvt_all_kernel<<<2048, 256, 0, stream>>>(
      slots, Abf, M * 1024 / 4,
      in_w, Winb, 3072 * 1024 / 4,
      out_w, Woutb, 1024 * 1024 / 4);

  // qkv = Abf @ Winb^T + in_b : M x 3072, tiles 384 x 12
  gemm256_bt_bias<<<384 * 12, 1024, 0, stream>>>(
      Abf, Winb, in_b, qkv, 3072, 1024, 1024, 3072, 12);

  // ctx written in-place into the k-slice of qkv
  attn3_kernel<<<2048, 256, 0, stream>>>(qkv);

  // attn_out = ctx @ Woutb^T + out_b -> q-slice of qkv : M x 1024, tiles 384 x 4
  gemm256_bt_bias<<<384 * 4, 1024, 0, stream>>>(
      qkv + 1024, Woutb, out_b, qkv, 1024, 1024, 3072, 3072, 4);

  // out = LN(slots_bf16 + attn_out) * g + b
  ln_kernel<<<M / 4, 256, 0, stream>>>(Abf, qkv, ln_g, ln_b, out);
}

// Round 20
// 1272.033 us; speedup vs baseline: 1.0456x; 1.0456x over previous
//
#include <hip/hip_runtime.h>
#include <stdint.h>

typedef unsigned short u16;
typedef float f32x4 __attribute__((ext_vector_type(4)));
typedef short bf16x8 __attribute__((ext_vector_type(8)));

// ---------- helpers ----------
__device__ __forceinline__ u16 f2bu(float f) {           // fp32 -> bf16 (RNE)
  uint32_t x = __builtin_bit_cast(uint32_t, f);
  x += 0x7fffu + ((x >> 16) & 1u);
  return (u16)(x >> 16);
}
__device__ __forceinline__ float b2f(u16 u) {            // bf16 -> fp32 (exact)
  return __builtin_bit_cast(float, (uint32_t)u << 16);
}
__device__ __forceinline__ void gll16(const void* g, void* l) {
  __builtin_amdgcn_global_load_lds(
      (const __attribute__((address_space(1))) void*)g,
      (__attribute__((address_space(3))) void*)l, 16, 0, 0);
}

// ---------- fused fp32 -> bf16 convert (3 tensors, one launch) ----------
__global__ __launch_bounds__(256) void cvt_all_kernel(
    const float* __restrict__ s, u16* __restrict__ os, int ns4,
    const float* __restrict__ w1, u16* __restrict__ o1, int n14,
    const float* __restrict__ w2, u16* __restrict__ o2, int n24) {
  const int stride = gridDim.x * 256;
  const int t0 = blockIdx.x * 256 + threadIdx.x;
  for (int i = t0; i < ns4; i += stride) {
    f32x4 f = __builtin_nontemporal_load(&reinterpret_cast<const f32x4*>(s)[i]);
    ushort4 o;
    o.x = f2bu(f.x); o.y = f2bu(f.y); o.z = f2bu(f.z); o.w = f2bu(f.w);
    reinterpret_cast<ushort4*>(os)[i] = o;
  }
  for (int i = t0; i < n14; i += stride) {
    f32x4 f = __builtin_nontemporal_load(&reinterpret_cast<const f32x4*>(w1)[i]);
    ushort4 o;
    o.x = f2bu(f.x); o.y = f2bu(f.y); o.z = f2bu(f.z); o.w = f2bu(f.w);
    reinterpret_cast<ushort4*>(o1)[i] = o;
  }
  for (int i = t0; i < n24; i += stride) {
    f32x4 f = __builtin_nontemporal_load(&reinterpret_cast<const f32x4*>(w2)[i]);
    ushort4 o;
    o.x = f2bu(f.x); o.y = f2bu(f.y); o.z = f2bu(f.z); o.w = f2bu(f.w);
    reinterpret_cast<ushort4*>(o2)[i] = o;
  }
}

// ---------- 256x256 GEMM, 16 waves, wave-tile 64x64, BK=64 (r12 best) ----
// C[m,n] = sum_k A[m,k]*B[n,k] + bias[n], bf16 in/out, fp32 accum.
// Schedule = r12/r18 structure (622-660us, MfmaUtil 46%, 0 conflicts).
// r20 delta: 4mt x 3nt SUPERTILE tile-order for ntn==12. Row-major order
// cycled the full 6MB B through the 4MB XCD-L2 every mt-row -> B re-fetched
// from HBM each row (FETCH 0.9-1.0GB vs 0.21 ideal; staging demand 3.2TB/s
// > measured 2.3-2.7TB/s => staging HBM-throughput-limited). Supertile
// working set = 4 A-panels (2MB) + 3 B-panels (1.5MB) = 3.5MB < 4MB L2.
// ntn==4 (GEMM2): B = 2MB, L2-resident -> keep simple mapping.
__global__ __launch_bounds__(1024, 4) void gemm256_bt_bias(
    const u16* __restrict__ A, const u16* __restrict__ Bw,
    const float* __restrict__ bias, u16* __restrict__ C,
    int N, int K, int lda, int ldc, int ntn) {
  __shared__ u16 lds[2][2][16384];   // [buf][A=0/B=1][256 rows * 64 cols]
  const int tid = threadIdx.x;
  const int lane = tid & 63, wid = tid >> 6;   // wid 0..15
  const int wr = wid >> 2, wc = wid & 3;        // wave grid 4 (M) x 4 (N)
  const int fr = lane & 15, kg = lane >> 4;

  // XCD-aware tile mapping (grid % 8 == 0 for both calls)
  const int bid = blockIdx.x;
  const int xcd = bid & 7;
  const int lid = bid >> 3;                 // local tile id within XCD
  int mt, nt;
  if (ntn == 12) {
    // supertile 4mt x 3nt: 12 tiles per supergroup, 48 groups/XCD (12x4)
    const int super = lid / 12, sub = lid % 12;
    mt = xcd * 48 + (super >> 2) * 4 + sub / 3;
    nt = (super & 3) * 3 + sub % 3;
  } else {
    const int cpx = (int)gridDim.x >> 3;    // tiles per XCD
    const int sid = xcd * cpx + lid;
    mt = sid / ntn;
    nt = sid % ntn;
  }

  // staging: slot s in {tid, tid+1024}; row = s>>3, slot3 = s&7.
  const int srow = tid >> 3;                    // 0..127 (slot 2 adds 128)
  const int sc8 = (tid & 7) ^ (srow & 7);
  const u16* Ag = A + (size_t)(mt * 256 + srow) * lda + sc8 * 8;
  const u16* Bg = Bw + (size_t)(nt * 256 + srow) * K + sc8 * 8;
  const size_t arstep = (size_t)128 * lda;     // +128 rows for slot 2
  const size_t brstep = (size_t)128 * K;

  // fragment read bases (u16, row stride 64); slot3 = ((kh<<2)|kg) ^ (fr&7)
  const int fx = fr & 7;
  const int aoff = (wr * 64 + fr) * 64;         // + mi*1024 + slot3*8
  const int boff = (wc * 64 + fr) * 64;         // + nj*1024 + slot3*8

  f32x4 acc[4][4];
#pragma unroll
  for (int i = 0; i < 4; i++)
#pragma unroll
    for (int j = 0; j < 4; j++) acc[i][j] = f32x4{0.f, 0.f, 0.f, 0.f};

  const int NT = K >> 6;

#define STAGE(b, kt) do {                                                  \
    const u16* a_ = Ag + (size_t)(kt) * 64;                                \
    const u16* b_ = Bg + (size_t)(kt) * 64;                                \
    gll16(a_,          &lds[(b)][0][wid * 512]);                           \
    gll16(a_ + arstep, &lds[(b)][0][8192 + wid * 512]);                    \
    gll16(b_,          &lds[(b)][1][wid * 512]);                           \
    gll16(b_ + brstep, &lds[(b)][1][8192 + wid * 512]);                    \
  } while (0)

  STAGE(0, 0);
  __syncthreads();              // tile 0 landed (vmcnt(0) drain)

  for (int t = 0; t < NT; t++) {
    const int cur = t & 1;
    if (t + 1 < NT) STAGE(cur ^ 1, t + 1);   // prefetch next tile
    const u16* As = &lds[cur][0][0];
    const u16* Bs = &lds[cur][1][0];
#pragma unroll
    for (int kh = 0; kh < 2; kh++) {         // two k-sub rounds, no barrier
      const int slot3 = ((kh << 2) | kg) ^ fx;
      bf16x8 a[4], b[4];
#pragma unroll
      for (int nj = 0; nj < 4; nj++)
        b[nj] = *(const bf16x8*)&Bs[boff + nj * 1024 + slot3 * 8];
#pragma unroll
      for (int mi = 0; mi < 4; mi++)
        a[mi] = *(const bf16x8*)&As[aoff + mi * 1024 + slot3 * 8];
      __builtin_amdgcn_s_setprio(1);
#pragma unroll
      for (int mi = 0; mi < 4; mi++)
#pragma unroll
        for (int nj = 0; nj < 4; nj++)
          acc[mi][nj] = __builtin_amdgcn_mfma_f32_16x16x32_bf16(
              a[mi], b[nj], acc[mi][nj], 0, 0, 0);
      __builtin_amdgcn_s_setprio(0);
    }
    __syncthreads();   // next tile landed + this tile's reads done (WAR safe)
  }
#undef STAGE

  // C/D layout per 16x16 frag: col = lane&15, row = (lane>>4)*4 + reg
  const int crow0 = mt * 256 + wr * 64 + kg * 4;
  const int ccol0 = nt * 256 + wc * 64 + fr;
#pragma unroll
  for (int nj = 0; nj < 4; nj++) {
    const int col = ccol0 + nj * 16;
    const float bb = bias[col];
#pragma unroll
    for (int mi = 0; mi < 4; mi++) {
      const int r0 = crow0 + mi * 16;
      f32x4 v = acc[mi][nj];
#pragma unroll
      for (int r = 0; r < 4; r++)
        C[(size_t)(r0 + r) * ldc + col] = f2bu(v[r] + bb);
    }
  }
}

// ---------- tiny attention: S=3, 16 heads of d=64, 16B/lane ----------
__global__ __launch_bounds__(256) void attn3_kernel(
    u16* __restrict__ qkv) {
  const int tid = threadIdx.x;
  const int lane = tid & 63, wid = tid >> 6;
  const int nunit = 32768 * 2;
  for (int unit = blockIdx.x * 4 + wid; unit < nunit; unit += gridDim.x * 4) {
    const int b = unit >> 1, hf = unit & 1;
    const int colb = hf * 512 + (lane >> 3) * 64 + (lane & 7) * 8;
    const size_t base = (size_t)b * 9216 + colb;

    float q[3][8], k[3][8], v[3][8];
#pragma unroll
    for (int s = 0; s < 3; s++) {
      bf16x8 uq = __builtin_nontemporal_load(
          (const bf16x8*)(qkv + base + (size_t)s * 3072));
      bf16x8 uk = __builtin_nontemporal_load(
          (const bf16x8*)(qkv + base + (size_t)s * 3072 + 1024));
      bf16x8 uv = __builtin_nontemporal_load(
          (const bf16x8*)(qkv + base + (size_t)s * 3072 + 2048));
#pragma unroll
      for (int e = 0; e < 8; e++) {
        q[s][e] = b2f((u16)uq[e]);
        k[s][e] = b2f((u16)uk[e]);
        v[s][e] = b2f((u16)uv[e]);
      }
    }

    float sc[3][3];
#pragma unroll
    for (int i = 0; i < 3; i++)
#pragma unroll
      for (int j = 0; j < 3; j++) {
        float p = 0.f;
#pragma unroll
        for (int e = 0; e < 8; e++) p += q[i][e] * k[j][e];
        p += __shfl_xor(p, 1);
        p += __shfl_xor(p, 2);
        p += __shfl_xor(p, 4);   // 8-lane group = one head's 64 dims
        sc[i][j] = p;
      }

    float o[3][8];
#pragma unroll
    for (int i = 0; i < 3; i++) {
      float mx = fmaxf(sc[i][0], fmaxf(sc[i][1], sc[i][2]));
      float e0 = __expf((sc[i][0] - mx) * 0.125f);
      float e1 = __expf((sc[i][1] - mx) * 0.125f);
      float e2 = __expf((sc[i][2] - mx) * 0.125f);
      float inv = 1.f / (e0 + e1 + e2);
      e0 *= inv; e1 *= inv; e2 *= inv;
#pragma unroll
      for (int e = 0; e < 8; e++)
        o[i][e] = e0 * v[0][e] + e1 * v[1][e] + e2 * v[2][e];
    }

#pragma unroll
    for (int i = 0; i < 3; i++) {
      bf16x8 ov;
#pragma unroll
      for (int e = 0; e < 8; e++) ov[e] = (short)f2bu(o[i][e]);
      *(bf16x8*)(qkv + base + (size_t)i * 3072 + 1024) = ov;
    }
  }
}

// ---------- residual + LayerNorm: wave per row of 1024, 16B loads ----------
__global__ __launch_bounds__(256) void ln_kernel(
    const u16* __restrict__ slots_bf, const u16* __restrict__ ao,
    const float* __restrict__ g, const float* __restrict__ bvec,
    float* __restrict__ out) {
  const int tid = threadIdx.x;
  const int lane = tid & 63, wid = tid >> 6;
  const int row = blockIdx.x * 4 + wid;
  const size_t rb = (size_t)row * 1024;
  const size_t ab = (size_t)row * 3072;

  float y[16];
  float sum = 0.f, sq = 0.f;
#pragma unroll
  for (int c = 0; c < 2; c++) {
    const int col = c * 512 + lane * 8;
    bf16x8 s8 = __builtin_nontemporal_load((const bf16x8*)(slots_bf + rb + col));
    bf16x8 a8 = __builtin_nontemporal_load((const bf16x8*)(ao + ab + col));
#pragma unroll
    for (int e = 0; e < 8; e++) {
      float yv = b2f((u16)s8[e]) + b2f((u16)a8[e]);
      y[c * 8 + e] = yv;
      sum += yv;
      sq += yv * yv;
    }
  }
#pragma unroll
  for (int m = 1; m < 64; m <<= 1) {
    sum += __shfl_xor(sum, m);
    sq  += __shfl_xor(sq, m);
  }
  const float mu = sum * (1.0f / 1024.0f);
  const float var = sq * (1.0f / 1024.0f) - mu * mu;
  const float rs = rsqrtf(var + 1e-5f);
#pragma unroll
  for (int c = 0; c < 2; c++) {
    const int col = c * 512 + lane * 8;
#pragma unroll
    for (int h = 0; h < 2; h++) {
      const float* gp = g + col + h * 4;
      const float* bp = bvec + col + h * 4;
      f32x4 gg = *reinterpret_cast<const f32x4*>(gp);
      f32x4 bb = *reinterpret_cast<const f32x4*>(bp);
      f32x4 ov;
      ov.x = (y[c * 8 + h * 4 + 0] - mu) * rs * gg.x + bb.x;
      ov.y = (y[c * 8 + h * 4 + 1] - mu) * rs * gg.y + bb.y;
      ov.z = (y[c * 8 + h * 4 + 2] - mu) * rs * gg.z + bb.z;
      ov.w = (y[c * 8 + h * 4 + 3] - mu) * rs * gg.w + bb.w;
      __builtin_nontemporal_store(ov, reinterpret_cast<f32x4*>(out + rb + col + h * 4));
    }
  }
}

extern "C" void kernel_launch(void* const* d_in, const int* in_sizes, int n_in,
                              void* d_out, int out_size, void* d_ws, size_t ws_size,
                              hipStream_t stream) {
  const float* slots = (const float*)d_in[0];
  const float* in_w  = (const float*)d_in[1];
  const float* in_b  = (const float*)d_in[2];
  const float* out_w = (const float*)d_in[3];
  const float* out_b = (const float*)d_in[4];
  const float* ln_g  = (const float*)d_in[5];
  const float* ln_b  = (const float*)d_in[6];
  float* out = (float*)d_out;

  const int M = 32768 * 3;  // 98304 rows

  // workspace layout:
  //   Abf   [M*1024 bf16] = 201,326,592 B   (stays live: bf16 slots for ln)
  //   Winb  [3072*1024]   =   6,291,456 B
  //   Woutb [1024*1024]   =   2,097,152 B
  //   qkv   [M*3072]      = 603,979,776 B   (k-slice reused as ctx,
  //                                          q-slice reused as attn_out)
  char* ws = (char*)d_ws;
  u16* Abf   = (u16*)ws;
  u16* Winb  = (u16*)(ws + 201326592);
  u16* Woutb = (u16*)(ws + 207618048);
  u16* qkv   = (u16*)(ws + 209715200);

  cvt_all_kernel<<<2048, 256, 0, stream>>>(
      slots, Abf, M * 1024 / 4,
      in_w, Winb, 3072 * 1024 / 4,
      out_w, Woutb, 1024 * 1024 / 4);

  // qkv = Abf @ Winb^T + in_b : M x 3072, tiles 384 x 12
  gemm256_bt_bias<<<384 * 12, 1024, 0, stream>>>(
      Abf, Winb, in_b, qkv, 3072, 1024, 1024, 3072, 12);

  // ctx written in-place into the k-slice of qkv
  attn3_kernel<<<2048, 256, 0, stream>>>(qkv);

  // attn_out = ctx @ Woutb^T + out_b -> q-slice of qkv : M x 1024, tiles 384 x 4
  gemm256_bt_bias<<<384 * 4, 1024, 0, stream>>>(
      qkv + 1024, Woutb, out_b, qkv, 1024, 1024, 3072, 3072, 4);

  // out = LN(slots_bf16 + attn_out) * g + b
  ln_kernel<<<M / 4, 256, 0, stream>>>(Abf, qkv, ln_g, ln_b, out);
}